// Round 7
// baseline (398.707 us; speedup 1.0000x reference)
//
#include <hip/hip_runtime.h>
#include <stdint.h>

// ---------------- types & helpers ----------------
typedef __bf16   bf16x8 __attribute__((ext_vector_type(8)));
typedef float    f32x4  __attribute__((ext_vector_type(4)));
typedef uint16_t u16x8  __attribute__((ext_vector_type(8)));
typedef uint16_t u16x4  __attribute__((ext_vector_type(4)));

#define DEVFN static __device__ __forceinline__

DEVFN uint16_t f2bf(float f){            // RNE f32 -> bf16
  uint32_t u = __builtin_bit_cast(uint32_t, f);
  u += 0x7fffu + ((u >> 16) & 1u);
  return (uint16_t)(u >> 16);
}
DEVFN float bf2f(uint16_t h){
  return __builtin_bit_cast(float, (uint32_t)h << 16);
}
DEVFN bf16x8 ldbf8(const uint16_t* p){
  return __builtin_bit_cast(bf16x8, *(const u16x8*)p);
}
DEVFN void gl16(const void* g, void* l){ // async global->LDS, 16B/lane, LDS base wave-uniform
  __builtin_amdgcn_global_load_lds((__attribute__((address_space(1))) void*)g,
                                   (__attribute__((address_space(3))) void*)l,
                                   16, 0, 0);
}
DEVFN f32x4 mfma16(bf16x8 a, bf16x8 b, f32x4 c){
  return __builtin_amdgcn_mfma_f32_16x16x32_bf16(a, b, c, 0, 0, 0);
}

// ---------------- mask dtype detect + expand ----------------
__global__ void detect_mask_k(const uint32_t* m, int* flag){
  int notint = 0, notfloat = 0;
  for (int i = threadIdx.x; i < 4096; i += 256){
    uint32_t v = m[i];
    notint   |= (v > 1u) ? 1 : 0;
    notfloat |= (v != 0u && v != 0x3F800000u) ? 1 : 0;
  }
  int bits = notint | (notfloat << 1);
  if (bits) atomicOr(flag, bits);
}

__global__ void expand_mask_k(const void* m, const int* flag, float* bias){
  int i = blockIdx.x * 256 + threadIdx.x;   // 16384 elements
  int f = *flag;
  bool on;
  if ((f & 1) == 0)      on = ((const int*)m)[i]   != 0;     // int32
  else if ((f & 2) == 0) on = ((const float*)m)[i] != 0.0f;  // float32
  else                   on = ((const uint8_t*)m)[i] != 0;   // bool bytes
  bias[i] = on ? 0.0f : -1e30f;
}

// ---------------- RMSNorm (f32 in) -> bf16 out ----------------
__global__ __launch_bounds__(256) void rmsnorm_k(const float* __restrict__ in,
                                                 uint16_t* __restrict__ out,
                                                 const float* __restrict__ scale){
  int row = blockIdx.x;
  const float4* ip = (const float4*)(in + (size_t)row * 1024);
  float4 v = ip[threadIdx.x];
  float ss = v.x*v.x + v.y*v.y + v.z*v.z + v.w*v.w;
  #pragma unroll
  for (int off = 1; off < 64; off <<= 1) ss += __shfl_xor(ss, off);
  __shared__ float wsum[4];
  if ((threadIdx.x & 63) == 0) wsum[threadIdx.x >> 6] = ss;
  __syncthreads();
  float r = rsqrtf((wsum[0] + wsum[1] + wsum[2] + wsum[3]) * (1.0f/1024.0f) + 1e-6f);
  float4 sc = ((const float4*)scale)[threadIdx.x];
  u16x4 o;
  o[0] = f2bf(v.x * r * (1.0f + sc.x));
  o[1] = f2bf(v.y * r * (1.0f + sc.y));
  o[2] = f2bf(v.z * r * (1.0f + sc.z));
  o[3] = f2bf(v.w * r * (1.0f + sc.w));
  *(u16x4*)(out + (size_t)row * 1024 + threadIdx.x * 4) = o;
}

// ---------------- transpose+cast: f32 [R][C] -> bf16 [C][R] (batched) ----------------
__global__ void transpose_cast_k(const float* __restrict__ in, uint16_t* __restrict__ out,
                                 int rs, int os, long ibs, long obs){
  __shared__ float t[32][33];
  const float* ip = in  + (size_t)blockIdx.z * ibs;
  uint16_t*    op = out + (size_t)blockIdx.z * obs;
  int c0 = blockIdx.x * 32, r0 = blockIdx.y * 32;
  int tx = threadIdx.x, ty = threadIdx.y;     // (32,8)
  #pragma unroll
  for (int i = 0; i < 4; ++i)
    t[ty + 8*i][tx] = ip[(size_t)(r0 + ty + 8*i) * rs + c0 + tx];
  __syncthreads();
  #pragma unroll
  for (int i = 0; i < 4; ++i)
    op[(size_t)(c0 + ty + 8*i) * os + r0 + tx] = f2bf(t[tx][ty + 8*i]);
}

// ---------------- RoPE (in-place on bf16) ----------------
__global__ __launch_bounds__(256) void rope_q_k(uint16_t* q){
  int idx = blockIdx.x * 256 + threadIdx.x;     // 2M pairs
  int j = idx & 127, n = (idx >> 7) & 3, bt = idx >> 9;
  float inv = exp2f((float)j * (-13.287712379549449f / 128.0f)); // 10000^(-j/128)
  float rad = (float)(2048 + (bt & 511)) * inv;
  float s, c; sincosf(rad, &s, &c);
  size_t base = (size_t)bt * 1024 + n * 256 + j;
  float x1 = bf2f(q[base]), x2 = bf2f(q[base + 128]);
  q[base]       = f2bf((x1 * c - x2 * s) * 0.0625f);
  q[base + 128] = f2bf((x2 * c + x1 * s) * 0.0625f);
}
__global__ __launch_bounds__(256) void rope_k_k(uint16_t* kk){
  int idx = blockIdx.x * 256 + threadIdx.x;     // 2M pairs
  int j = idx & 127, bs = idx >> 7;
  float inv = exp2f((float)j * (-13.287712379549449f / 128.0f));
  float rad = (float)(bs & 2047) * inv;
  float s, c; sincosf(rad, &s, &c);
  size_t base = (size_t)bs * 256 + j;
  float x1 = bf2f(kk[base]), x2 = bf2f(kk[base + 128]);
  kk[base]       = f2bf(x1 * c - x2 * s);
  kk[base + 128] = f2bf(x2 * c + x1 * s);
}

// ---------------- GEMM: C[M][N] = A[M][K] * Bt[N][K]^T  (bf16 in, m97 structure) ----------------
template<int EPI>
__global__ __launch_bounds__(256) void gemm_bt_k(const uint16_t* __restrict__ A,
                                                 const uint16_t* __restrict__ Bt,
                                                 float* Cf, uint16_t* Cb,
                                                 uint16_t* Ko, uint16_t* Vto,
                                                 int M, int N, int K){
  int n0 = blockIdx.x * 128, m0 = blockIdx.y * 128;
  int tid = threadIdx.x, lane = tid & 63, wid = tid >> 6;
  int wr = wid >> 1, wc = wid & 1;
  int lr = lane & 15, lq = lane >> 4;
  __shared__ __align__(16) uint16_t As[128*32];
  __shared__ __align__(16) uint16_t Bs[128*32];
  f32x4 acc[4][4] = {};
  #pragma unroll 1
  for (int k0 = 0; k0 < K; k0 += 32){
    __syncthreads();
    #pragma unroll
    for (int it = 0; it < 2; ++it){
      int ob = it * 4096 + tid * 16;
      int row = ob >> 6, col = ob & 63;
      gl16((const char*)A  + ((size_t)(m0 + row) * K + k0) * 2 + col,
           (char*)As + it * 4096 + wid * 1024);
      gl16((const char*)Bt + ((size_t)(n0 + row) * K + k0) * 2 + col,
           (char*)Bs + it * 4096 + wid * 1024);
    }
    __syncthreads();
    bf16x8 af[4], bfr[4];
    #pragma unroll
    for (int m = 0; m < 4; ++m)  af[m]  = ldbf8(&As[(wr*64 + m*16 + lr) * 32 + lq * 8]);
    #pragma unroll
    for (int n = 0; n < 4; ++n)  bfr[n] = ldbf8(&Bs[(wc*64 + n*16 + lr) * 32 + lq * 8]);
    #pragma unroll
    for (int m = 0; m < 4; ++m)
      #pragma unroll
      for (int n = 0; n < 4; ++n)
        acc[m][n] = mfma16(af[m], bfr[n], acc[m][n]);
  }
  #pragma unroll
  for (int m = 0; m < 4; ++m)
    #pragma unroll
    for (int n = 0; n < 4; ++n){
      int gr0 = m0 + wr*64 + m*16 + lq*4;
      int gc  = n0 + wc*64 + n*16 + lr;
      if constexpr (EPI == 0){
        #pragma unroll
        for (int r = 0; r < 4; ++r) Cf[(size_t)(gr0 + r) * N + gc] = acc[m][n][r];
      } else if constexpr (EPI == 1){
        #pragma unroll
        for (int r = 0; r < 4; ++r) Cb[(size_t)(gr0 + r) * N + gc] = f2bf(acc[m][n][r]);
      } else {
        if (gc < 256){
          #pragma unroll
          for (int r = 0; r < 4; ++r) Ko[(size_t)(gr0 + r) * 256 + gc] = f2bf(acc[m][n][r]);
        } else {
          int h = gc - 256, bb = gr0 >> 11, s0 = gr0 & 2047;
          u16x4 pk;
          #pragma unroll
          for (int r = 0; r < 4; ++r) pk[r] = f2bf(acc[m][n][r]);
          *(u16x4*)&Vto[((size_t)bb * 256 + h) * 2048 + s0] = pk;
        }
      }
    }
}

// ---------------- flash attention: round-3 structure + 2 blocks/CU + Vs swizzle ----------------
// grid 512 = sh(2b) x qt(4b) x b(3b low -> XCD pin). 512 threads = 8 waves.
// wave (mh = wid>>2, head n = wid&3): 16 q-rows of head n (one m-block).
// K/V staged ONCE per tile for all heads; 2-phase dbuf (STAGE next / compute cur /
// __syncthreads).  No vmem in the loop body except staging (bias pre-staged in LDS)
// so the implicit waits can't drain the prefetch.  LDS 74KB -> 2 blocks/CU,
// VGPR capped 128 -> 4 waves/SIMD (the round-3..5 structure had only 2).
// Ks swizzle: byte ^ ((row&7)<<4) (2-way).  Vs swizzle: byte ^ ((row&3)<<4)
// (16-way -> 4-way, the 4.2e6-conflict fix).  Both applied on the pre-swizzled
// global source (linear gl16 dest) and on the LDS read.
__global__ __launch_bounds__(512, 4) void attn_k(const uint16_t* __restrict__ Q,
                                                 const uint16_t* __restrict__ Kb,
                                                 const uint16_t* __restrict__ Vt,
                                                 const float* __restrict__ bias,
                                                 float* __restrict__ po,   // [3][4096][1024]
                                                 float* __restrict__ po3,  // [4096][1024] (=d_out)
                                                 float* __restrict__ pm,
                                                 float* __restrict__ pl){
  int bx = blockIdx.x;
  int b = bx & 7, qt = (bx >> 3) & 15, sh = bx >> 7;
  int tid = threadIdx.x, lane = tid & 63, wid = tid >> 6;
  int n = wid & 3, mh = wid >> 2;
  int lr = lane & 15, lq = lane >> 4;
  __shared__ __align__(16) uint16_t Ks[2*32*256];   // [buf][s][k], swizzled
  __shared__ __align__(16) uint16_t Vs[2*256*32];   // [buf][h][s], swizzled
  __shared__ __align__(16) uint16_t Ps[8][16*32];   // per-wave P tile, lq-swizzled
  __shared__ float bias_lds[512];

  int sbeg = sh * 512;
  bias_lds[tid] = bias[b*2048 + sbeg + tid];

  int t0 = qt*32 + mh*16;                           // wave's 16 q-rows
  bf16x8 qf[8];
  {
    const uint16_t* qp = Q + (size_t)(b*512 + t0 + lr) * 1024 + n*256 + lq*8;
    #pragma unroll
    for (int kc = 0; kc < 8; ++kc) qf[kc] = ldbf8(qp + kc*32);
  }
  f32x4 o[16] = {};
  float mrow[4] = {-1e30f, -1e30f, -1e30f, -1e30f};
  float lrow[4] = {0.f, 0.f, 0.f, 0.f};

  // ---- staging: 4 gl16/thread/tile (Ks 16KB + Vs 16KB over 512 lanes x 16B x 2) ----
  auto STAGE = [&](int buf, int s0){
    #pragma unroll
    for (int it = 0; it < 2; ++it){
      int ob = it*8192 + tid*16;
      int krow = ob >> 9;
      int kcol = (ob & 511) ^ ((krow & 7) << 4); // pre-swizzled source
      gl16((const char*)Kb + ((size_t)(b*2048 + s0 + krow) * 256) * 2 + kcol,
           (char*)Ks + buf*16384 + it*8192 + wid*1024);
      int vrow = ob >> 6;
      int vcol = (ob & 63) ^ ((vrow & 3) << 4);  // pre-swizzled source (NEW)
      gl16((const char*)Vt + ((size_t)(b*256 + vrow) * 2048 + s0) * 2 + vcol,
           (char*)Vs + buf*16384 + it*8192 + wid*1024);
    }
  };

  STAGE(0, sbeg);
  __syncthreads();                                  // tile 0 + bias ready

  #pragma unroll 1
  for (int t = 0; t < 16; ++t){
    if (t < 15) STAGE((t+1) & 1, sbeg + (t+1)*32); // flies under this tile's compute
    const uint16_t* ksb = Ks + (t & 1)*8192;
    const uint16_t* vsb = Vs + (t & 1)*8192;

    // QK^T: S[16q][32s] per wave
    f32x4 sacc[2] = {};
    __builtin_amdgcn_s_setprio(1);
    #pragma unroll
    for (int sc = 0; sc < 2; ++sc)
      #pragma unroll
      for (int kc = 0; kc < 8; ++kc){
        bf16x8 bk = ldbf8(&ksb[((sc*16 + lr)*256 + kc*32 + lq*8) ^ ((lr & 7) << 3)]);
        sacc[sc] = mfma16(qf[kc], bk, sacc[sc]);
      }
    __builtin_amdgcn_s_setprio(0);

    float b0 = bias_lds[t*32 + lr], b1 = bias_lds[t*32 + 16 + lr];
    float v[2][4], mxv[4];
    bool need = false;
    #pragma unroll
    for (int r = 0; r < 4; ++r){
      v[0][r] = sacc[0][r] + b0;
      v[1][r] = sacc[1][r] + b1;
      float m0 = fmaxf(v[0][r], v[1][r]);
      m0 = fmaxf(m0, __shfl_xor(m0, 1));
      m0 = fmaxf(m0, __shfl_xor(m0, 2));
      m0 = fmaxf(m0, __shfl_xor(m0, 4));
      m0 = fmaxf(m0, __shfl_xor(m0, 8));
      mxv[r] = m0;
      need = need || (m0 > mrow[r] + 8.0f);
    }
    if (__any(need)){                            // defer-max (T13)
      float sf[4];
      #pragma unroll
      for (int r = 0; r < 4; ++r){
        float mn2 = fmaxf(mrow[r], mxv[r]);
        float s = __expf(mrow[r] - mn2);
        mrow[r] = mn2; lrow[r] *= s; sf[r] = s;
      }
      #pragma unroll
      for (int hf = 0; hf < 16; ++hf){
        f32x4 tt = o[hf];
        tt[0] *= sf[0]; tt[1] *= sf[1]; tt[2] *= sf[2]; tt[3] *= sf[3];
        o[hf] = tt;
      }
    }
    #pragma unroll
    for (int r = 0; r < 4; ++r){
      float p0 = __expf(v[0][r] - mrow[r]);
      float p1 = __expf(v[1][r] - mrow[r]);
      float rs = p0 + p1;
      rs += __shfl_xor(rs, 1);
      rs += __shfl_xor(rs, 2);
      rs += __shfl_xor(rs, 4);
      rs += __shfl_xor(rs, 8);
      lrow[r] += rs;
      int q = lq*4 + r;
      Ps[wid][(q*32 + lr)      ^ (lq << 4)] = f2bf(p0);  // same-wave DS, in-order
      Ps[wid][(q*32 + 16 + lr) ^ (lq << 4)] = f2bf(p1);
    }
    bf16x8 pa = ldbf8(&Ps[wid][(lr*32 + lq*8) ^ (((lr >> 2) & 3) << 4)]);
    __builtin_amdgcn_s_setprio(1);
    #pragma unroll
    for (int hf = 0; hf < 16; ++hf){
      bf16x8 bv = ldbf8(&vsb[((hf*16 + lr)*32 + lq*8) ^ ((lr & 3) << 3)]);
      o[hf] = mfma16(pa, bv, o[hf]);
    }
    __builtin_amdgcn_s_setprio(0);
    __syncthreads();                 // drains staging: next tile ready, buffers reusable
  }

  // epilogue: unscaled partial o (f32) + per-row m,l
  float* pop = (sh == 3) ? po3 : po + (size_t)sh * 4194304;
  int trow = t0 + lq*4;
  #pragma unroll
  for (int hf = 0; hf < 16; ++hf)
    #pragma unroll
    for (int r = 0; r < 4; ++r)
      pop[(size_t)(b*512 + trow + r)*1024 + n*256 + hf*16 + lr] = o[hf][r];
  if (lr == 0)
    #pragma unroll
    for (int r = 0; r < 4; ++r){
      int mlidx = sh*16384 + (b*512 + trow + r)*4 + n;
      pm[mlidx] = mrow[r];
      pl[mlidx] = lrow[r];
    }
}

// ---------------- merge split-S partials -> enc bf16 ----------------
__global__ __launch_bounds__(64) void merge_k(const float* __restrict__ po,
                                              const float* __restrict__ po3,
                                              const float* __restrict__ pm,
                                              const float* __restrict__ pl,
                                              uint16_t* __restrict__ enc){
  int idx = blockIdx.x;                  // 16384 = (b*512+t)*4 + n
  int row = idx >> 2, n = idx & 3;
  float m = -1e30f;
  #pragma unroll
  for (int h = 0; h < 4; ++h) m = fmaxf(m, pm[h*16384 + idx]);
  float w[4], lsum = 0.0f;
  #pragma unroll
  for (int h = 0; h < 4; ++h){
    w[h] = __expf(pm[h*16384 + idx] - m);
    lsum += pl[h*16384 + idx] * w[h];
  }
  float inv = 1.0f / lsum;
  size_t off = (size_t)row*1024 + n*256 + threadIdx.x*4;
  f32x4 acc = {};
  #pragma unroll
  for (int h = 0; h < 3; ++h){
    f32x4 a = *(const f32x4*)(po + (size_t)h*4194304 + off);
    acc[0] += a[0]*w[h]; acc[1] += a[1]*w[h]; acc[2] += a[2]*w[h]; acc[3] += a[3]*w[h];
  }
  f32x4 a3 = *(const f32x4*)(po3 + off);
  acc[0] += a3[0]*w[3]; acc[1] += a3[1]*w[3]; acc[2] += a3[2]*w[3]; acc[3] += a3[3]*w[3];
  u16x4 ov;
  #pragma unroll
  for (int r = 0; r < 4; ++r) ov[r] = f2bf(acc[r] * inv);
  *(u16x4*)(enc + off) = ov;
}

// ---------------- launcher ----------------
extern "C" void kernel_launch(void* const* d_in, const int* in_sizes, int n_in,
                              void* d_out, int out_size, void* d_ws, size_t ws_size,
                              hipStream_t stream){
  const float* x    = (const float*)d_in[0];   // [8][512][1024]
  const float* mem  = (const float*)d_in[1];   // [8][2048][1024]
  const void*  mask = d_in[2];                 // [8][2048]
  const float* rms  = (const float*)d_in[3];   // [1024]
  const float* qw   = (const float*)d_in[4];   // [4][1024][256]
  const float* kvw  = (const float*)d_in[5];   // [2][1][1024][256]
  const float* ow   = (const float*)d_in[6];   // [4][256][1024]
  float* out = (float*)d_out;                  // [8][512][1024] f32
  char* ws = (char*)d_ws;

  const size_t MB = 1ull << 20;
  uint16_t* xn   = (uint16_t*)(ws + 0);        // 8MB  bf16 [4096][1024]
  uint16_t* enc  = (uint16_t*)(ws + 0);        // 8MB  reuse (xn dead before merge)
  uint16_t* qb   = (uint16_t*)(ws + 8*MB);     // 8MB  q bf16 [4096][1024]
  uint16_t* kb   = (uint16_t*)(ws + 16*MB);    // 8MB  k bf16 [16384][256]
  uint16_t* vt   = (uint16_t*)(ws + 24*MB);    // 8MB  Vt bf16 [8][256][2048]
  uint16_t* wq   = (uint16_t*)(ws + 32*MB);    // 2MB
  uint16_t* wkv  = (uint16_t*)(ws + 34*MB);    // 1MB
  uint16_t* wout = (uint16_t*)(ws + 35*MB);    // 2MB
  float*    bias = (float*)   (ws + 37*MB);    // 64KB
  float*    pm   = (float*)   (ws + 37*MB + 65536);            // 256KB [4][16384]
  float*    pl   = (float*)   (ws + 37*MB + 65536 + 262144);   // 256KB
  int*      flag = (int*)     (ws + 37*MB + 65536 + 524288);
  uint16_t* mn   = (uint16_t*)(ws + 38*MB);    // 32MB bf16 [16384][1024] (dead after kv GEMM)
  float*    po   = (float*)   (ws + 38*MB);    // 48MB f32 [3][4096][1024] (reuses mn; top 86MB)
  float*    po3  = out;                        // 16MB 4th partial lives in d_out

  hipMemsetAsync(flag, 0, 4, stream);
  detect_mask_k<<<1, 256, 0, stream>>>((const uint32_t*)mask, flag);
  expand_mask_k<<<64, 256, 0, stream>>>(mask, flag, bias);

  rmsnorm_k<<<4096,  256, 0, stream>>>(x,   xn, rms);
  rmsnorm_k<<<16384, 256, 0, stream>>>(mem, mn, rms);

  transpose_cast_k<<<dim3(8,32,4),  dim3(32,8), 0, stream>>>(qw,  wq,   256, 1024, 1024*256, 256*1024);
  transpose_cast_k<<<dim3(8,32,2),  dim3(32,8), 0, stream>>>(kvw, wkv,  256, 1024, 1024*256, 256*1024);
  transpose_cast_k<<<dim3(32,32,1), dim3(32,8), 0, stream>>>(ow,  wout, 1024, 1024, 0, 0);

  gemm_bt_k<1><<<dim3(8, 32),  256, 0, stream>>>(xn, wq,  nullptr, qb, nullptr, nullptr, 4096, 1024, 1024);
  gemm_bt_k<2><<<dim3(4, 128), 256, 0, stream>>>(mn, wkv, nullptr, nullptr, kb, vt, 16384, 512, 1024);

  rope_q_k<<<8192, 256, 0, stream>>>(qb);
  rope_k_k<<<8192, 256, 0, stream>>>(kb);

  attn_k<<<512, 512, 0, stream>>>(qb, kb, vt, bias, po, po3, pm, pl);
  merge_k<<<16384, 64, 0, stream>>>(po, po3, pm, pl, enc);

  gemm_bt_k<0><<<dim3(8, 32), 256, 0, stream>>>(enc, wout, out, nullptr, nullptr, nullptr, 4096, 1024, 1024);
}

// Round 8
// 224.852 us; speedup vs baseline: 1.7732x; 1.7732x over previous
//
#include <hip/hip_runtime.h>
#include <stdint.h>

// ---------------- types & helpers ----------------
typedef __bf16   bf16x8 __attribute__((ext_vector_type(8)));
typedef float    f32x4  __attribute__((ext_vector_type(4)));
typedef float    f32x16 __attribute__((ext_vector_type(16)));
typedef uint16_t u16x8  __attribute__((ext_vector_type(8)));
typedef uint16_t u16x4  __attribute__((ext_vector_type(4)));
typedef uint32_t u32x4  __attribute__((ext_vector_type(4)));

#define DEVFN static __device__ __forceinline__

DEVFN uint16_t f2bf(float f){            // RNE f32 -> bf16
  uint32_t u = __builtin_bit_cast(uint32_t, f);
  u += 0x7fffu + ((u >> 16) & 1u);
  return (uint16_t)(u >> 16);
}
DEVFN float bf2f(uint16_t h){
  return __builtin_bit_cast(float, (uint32_t)h << 16);
}
DEVFN bf16x8 ldbf8(const uint16_t* p){
  return __builtin_bit_cast(bf16x8, *(const u16x8*)p);
}
DEVFN void gl16(const void* g, void* l){ // async global->LDS, 16B/lane, LDS base wave-uniform
  __builtin_amdgcn_global_load_lds((__attribute__((address_space(1))) void*)g,
                                   (__attribute__((address_space(3))) void*)l,
                                   16, 0, 0);
}
DEVFN f32x4 mfma16(bf16x8 a, bf16x8 b, f32x4 c){
  return __builtin_amdgcn_mfma_f32_16x16x32_bf16(a, b, c, 0, 0, 0);
}
DEVFN f32x16 mfma32(bf16x8 a, bf16x8 b, f32x16 c){
  return __builtin_amdgcn_mfma_f32_32x32x16_bf16(a, b, c, 0, 0, 0);
}
DEVFN uint32_t cvtpk(float lo, float hi){          // pack 2 f32 -> 2 bf16 in one dword
  uint32_t r;
  asm("v_cvt_pk_bf16_f32 %0, %1, %2" : "=v"(r) : "v"(lo), "v"(hi));
  return r;
}
DEVFN void plswap(uint32_t &x, uint32_t &y){       // swap x.hi-lanes <-> y.lo-lanes
  asm("v_permlane32_swap_b32 %0, %1" : "+v"(x), "+v"(y));
}

// ---------------- mask dtype detect + expand ----------------
__global__ void detect_mask_k(const uint32_t* m, int* flag){
  int notint = 0, notfloat = 0;
  for (int i = threadIdx.x; i < 4096; i += 256){
    uint32_t v = m[i];
    notint   |= (v > 1u) ? 1 : 0;
    notfloat |= (v != 0u && v != 0x3F800000u) ? 1 : 0;
  }
  int bits = notint | (notfloat << 1);
  if (bits) atomicOr(flag, bits);
}

__global__ void expand_mask_k(const void* m, const int* flag, float* bias){
  int i = blockIdx.x * 256 + threadIdx.x;   // 16384 elements
  int f = *flag;
  bool on;
  if ((f & 1) == 0)      on = ((const int*)m)[i]   != 0;     // int32
  else if ((f & 2) == 0) on = ((const float*)m)[i] != 0.0f;  // float32
  else                   on = ((const uint8_t*)m)[i] != 0;   // bool bytes
  bias[i] = on ? 0.0f : -1e30f;
}

// ---------------- RMSNorm (f32 in) -> bf16 out ----------------
__global__ __launch_bounds__(256) void rmsnorm_k(const float* __restrict__ in,
                                                 uint16_t* __restrict__ out,
                                                 const float* __restrict__ scale){
  int row = blockIdx.x;
  const float4* ip = (const float4*)(in + (size_t)row * 1024);
  float4 v = ip[threadIdx.x];
  float ss = v.x*v.x + v.y*v.y + v.z*v.z + v.w*v.w;
  #pragma unroll
  for (int off = 1; off < 64; off <<= 1) ss += __shfl_xor(ss, off);
  __shared__ float wsum[4];
  if ((threadIdx.x & 63) == 0) wsum[threadIdx.x >> 6] = ss;
  __syncthreads();
  float r = rsqrtf((wsum[0] + wsum[1] + wsum[2] + wsum[3]) * (1.0f/1024.0f) + 1e-6f);
  float4 sc = ((const float4*)scale)[threadIdx.x];
  u16x4 o;
  o[0] = f2bf(v.x * r * (1.0f + sc.x));
  o[1] = f2bf(v.y * r * (1.0f + sc.y));
  o[2] = f2bf(v.z * r * (1.0f + sc.z));
  o[3] = f2bf(v.w * r * (1.0f + sc.w));
  *(u16x4*)(out + (size_t)row * 1024 + threadIdx.x * 4) = o;
}

// ---------------- transpose+cast: f32 [R][C] -> bf16 [C][R] (batched) ----------------
__global__ void transpose_cast_k(const float* __restrict__ in, uint16_t* __restrict__ out,
                                 int rs, int os, long ibs, long obs){
  __shared__ float t[32][33];
  const float* ip = in  + (size_t)blockIdx.z * ibs;
  uint16_t*    op = out + (size_t)blockIdx.z * obs;
  int c0 = blockIdx.x * 32, r0 = blockIdx.y * 32;
  int tx = threadIdx.x, ty = threadIdx.y;     // (32,8)
  #pragma unroll
  for (int i = 0; i < 4; ++i)
    t[ty + 8*i][tx] = ip[(size_t)(r0 + ty + 8*i) * rs + c0 + tx];
  __syncthreads();
  #pragma unroll
  for (int i = 0; i < 4; ++i)
    op[(size_t)(c0 + ty + 8*i) * os + r0 + tx] = f2bf(t[tx][ty + 8*i]);
}

// ---------------- RoPE (in-place on bf16) ----------------
__global__ __launch_bounds__(256) void rope_q_k(uint16_t* q){
  int idx = blockIdx.x * 256 + threadIdx.x;     // 2M pairs
  int j = idx & 127, n = (idx >> 7) & 3, bt = idx >> 9;
  float inv = exp2f((float)j * (-13.287712379549449f / 128.0f)); // 10000^(-j/128)
  float rad = (float)(2048 + (bt & 511)) * inv;
  float s, c; sincosf(rad, &s, &c);
  size_t base = (size_t)bt * 1024 + n * 256 + j;
  float x1 = bf2f(q[base]), x2 = bf2f(q[base + 128]);
  q[base]       = f2bf((x1 * c - x2 * s) * 0.0625f);
  q[base + 128] = f2bf((x2 * c + x1 * s) * 0.0625f);
}
__global__ __launch_bounds__(256) void rope_k_k(uint16_t* kk){
  int idx = blockIdx.x * 256 + threadIdx.x;     // 2M pairs
  int j = idx & 127, bs = idx >> 7;
  float inv = exp2f((float)j * (-13.287712379549449f / 128.0f));
  float rad = (float)(bs & 2047) * inv;
  float s, c; sincosf(rad, &s, &c);
  size_t base = (size_t)bs * 256 + j;
  float x1 = bf2f(kk[base]), x2 = bf2f(kk[base + 128]);
  kk[base]       = f2bf(x1 * c - x2 * s);
  kk[base + 128] = f2bf(x2 * c + x1 * s);
}

// ---------------- GEMM: C[M][N] = A[M][K] * Bt[N][K]^T  (bf16 in, m97 structure) ----------------
template<int EPI>
__global__ __launch_bounds__(256) void gemm_bt_k(const uint16_t* __restrict__ A,
                                                 const uint16_t* __restrict__ Bt,
                                                 float* Cf, uint16_t* Cb,
                                                 uint16_t* Ko, uint16_t* Vto,
                                                 int M, int N, int K){
  int n0 = blockIdx.x * 128, m0 = blockIdx.y * 128;
  int tid = threadIdx.x, lane = tid & 63, wid = tid >> 6;
  int wr = wid >> 1, wc = wid & 1;
  int lr = lane & 15, lq = lane >> 4;
  __shared__ __align__(16) uint16_t As[128*32];
  __shared__ __align__(16) uint16_t Bs[128*32];
  f32x4 acc[4][4] = {};
  #pragma unroll 1
  for (int k0 = 0; k0 < K; k0 += 32){
    __syncthreads();
    #pragma unroll
    for (int it = 0; it < 2; ++it){
      int ob = it * 4096 + tid * 16;
      int row = ob >> 6, col = ob & 63;
      gl16((const char*)A  + ((size_t)(m0 + row) * K + k0) * 2 + col,
           (char*)As + it * 4096 + wid * 1024);
      gl16((const char*)Bt + ((size_t)(n0 + row) * K + k0) * 2 + col,
           (char*)Bs + it * 4096 + wid * 1024);
    }
    __syncthreads();
    bf16x8 af[4], bfr[4];
    #pragma unroll
    for (int m = 0; m < 4; ++m)  af[m]  = ldbf8(&As[(wr*64 + m*16 + lr) * 32 + lq * 8]);
    #pragma unroll
    for (int n = 0; n < 4; ++n)  bfr[n] = ldbf8(&Bs[(wc*64 + n*16 + lr) * 32 + lq * 8]);
    #pragma unroll
    for (int m = 0; m < 4; ++m)
      #pragma unroll
      for (int n = 0; n < 4; ++n)
        acc[m][n] = mfma16(af[m], bfr[n], acc[m][n]);
  }
  #pragma unroll
  for (int m = 0; m < 4; ++m)
    #pragma unroll
    for (int n = 0; n < 4; ++n){
      int gr0 = m0 + wr*64 + m*16 + lq*4;
      int gc  = n0 + wc*64 + n*16 + lr;
      if constexpr (EPI == 0){
        #pragma unroll
        for (int r = 0; r < 4; ++r) Cf[(size_t)(gr0 + r) * N + gc] = acc[m][n][r];
      } else if constexpr (EPI == 1){
        #pragma unroll
        for (int r = 0; r < 4; ++r) Cb[(size_t)(gr0 + r) * N + gc] = f2bf(acc[m][n][r]);
      } else {
        if (gc < 256){
          #pragma unroll
          for (int r = 0; r < 4; ++r) Ko[(size_t)(gr0 + r) * 256 + gc] = f2bf(acc[m][n][r]);
        } else {
          int h = gc - 256, bb = gr0 >> 11, s0 = gr0 & 2047;
          u16x4 pk;
          #pragma unroll
          for (int r = 0; r < 4; ++r) pk[r] = f2bf(acc[m][n][r]);
          *(u16x4*)&Vto[((size_t)bb * 256 + h) * 2048 + s0] = pk;
        }
      }
    }
}

// ---------------- flash attention: 32x32 MFMA + swapped QK^T + in-register softmax ----------------
// LDS-BW model: round-3 was LDS-bound (272KB/CU/tile = 2125cy ~= observed 2560cy/tile).
// This version: 32x32x16 MFMA halves fragment bytes (512B/read), swapped QK^T
// (mfma(K,Q)) makes each lane own one q-row -> softmax is in-register (15 ops +
// one shfl_xor(32)); P->A-frag via v_cvt_pk_bf16_f32 + v_permlane32_swap (no Ps
// LDS); mask as bit-words (no bias DS). Per-wave LDS/tile: 16KB (was 34KB).
// grid 256 = sh(2b) x qt(3b) x b(3b low, XCD pin). 512 thr = 8 waves =
// qs(2) x head n(4); wave owns 32 q-rows of head n, S-range 512, tiles of 32.
// Ks[s][k] XOR-swizzled (T2, pre-swizzled source); Vs subtiled [4 sc][256 h][8 s]
// -> 32x32 B-frag reads conflict-free. 2-phase dbuf; no vmem in loop except STAGE.
__global__ __launch_bounds__(512, 2) void attn_k(const uint16_t* __restrict__ Q,
                                                 const uint16_t* __restrict__ Kb,
                                                 const uint16_t* __restrict__ Vt,
                                                 const float* __restrict__ bias,
                                                 float* __restrict__ po,   // [3][4096][1024]
                                                 float* __restrict__ po3,  // [4096][1024] (=d_out)
                                                 float* __restrict__ pm,
                                                 float* __restrict__ pl){
  int bx = blockIdx.x;
  int b = bx & 7, qt = (bx >> 3) & 7, sh = bx >> 6;
  int tid = threadIdx.x, lane = tid & 63, wid = tid >> 6;
  int n = wid & 3, qs = wid >> 2;
  int lc = lane & 31, hi = lane >> 5;
  __shared__ __align__(16) uint16_t Ks[2*32*256];   // [buf][s][k], swizzled
  __shared__ __align__(16) uint16_t Vs[2*4*256*8];  // [buf][sc][h][8s], subtiled
  __shared__ uint32_t mask_lds[16];

  int sbeg = sh * 512;
  {
    float bv = bias[b*2048 + sbeg + tid];           // one vmem read, prologue only
    unsigned long long bal = __ballot(bv == 0.0f);  // wave wid covers s [wid*64, wid*64+64)
    if (lane == 0){
      mask_lds[wid*2]     = (uint32_t)bal;
      mask_lds[wid*2 + 1] = (uint32_t)(bal >> 32);
    }
  }

  int t0w = qt*64 + qs*32;                          // wave's 32 q-rows
  // Q as B-operand frags: lane holds Q[q = t0w+lc][d = kc*16 + hi*8 .. +7]
  bf16x8 qf[16];
  {
    const uint16_t* qp = Q + (size_t)(b*512 + t0w + lc) * 1024 + n*256 + hi*8;
    #pragma unroll
    for (int kc = 0; kc < 16; ++kc) qf[kc] = ldbf8(qp + kc*16);
  }
  f32x16 o[8] = {};                                 // O[32q][256h]: lane: col h=ht*32+lc, 16 q-rows
  float mrow = -1e30f, lrow = 0.0f;                 // per-lane = per-q (lanes L, L^32 duplicate)

  auto STAGE = [&](int buf, int s0){
    #pragma unroll
    for (int it = 0; it < 2; ++it){
      int ob = it*8192 + tid*16;
      int krow = ob >> 9;                           // K: [32 s][512B], XOR-pre-swizzled source
      int kcol = (ob & 511) ^ ((krow & 7) << 4);
      gl16((const char*)Kb + ((size_t)(b*2048 + s0 + krow) * 256) * 2 + kcol,
           (char*)Ks + buf*16384 + it*8192 + wid*1024);
      int sc = ob >> 12;                            // V: LDS q = sc*4096 + h*16 + ds*2
      int h  = (ob >> 4) & 255;
      gl16((const char*)Vt + ((size_t)(b*256 + h) * 2048 + s0 + sc*8) * 2,
           (char*)Vs + buf*16384 + it*8192 + wid*1024);
    }
  };

  STAGE(0, sbeg);
  __syncthreads();                                  // tile 0 + mask words ready

  #pragma unroll 1
  for (int t = 0; t < 16; ++t){
    if (t < 15) STAGE((t+1) & 1, sbeg + (t+1)*32); // flies under this tile's compute
    const uint16_t* ksb = Ks + (t & 1)*8192;
    const uint16_t* vsb = Vs + (t & 1)*8192;

    // swapped QK^T: C[s][q], col = q = lc, row s = (reg&3)+8*(reg>>2)+4*hi
    f32x16 sacc = {};
    __builtin_amdgcn_s_setprio(1);
    #pragma unroll
    for (int kc = 0; kc < 16; ++kc){
      bf16x8 ak = ldbf8(&ksb[lc*256 + ((kc*16 + hi*8) ^ ((lc & 7) << 3))]);
      sacc = mfma32(ak, qf[kc], sacc);
    }
    __builtin_amdgcn_s_setprio(0);

    // in-register masked online softmax (lane owns q = lc; s-subset in 16 regs)
    uint32_t mw = mask_lds[t];
    int sb4 = hi * 4;
    float p[16];
    float mx = -1e30f;
    #pragma unroll
    for (int r = 0; r < 16; ++r){
      int sr = (r & 3) + 8*(r >> 2) + sb4;
      float v = ((mw >> sr) & 1u) ? sacc[r] : -1e30f;
      p[r] = v;
      mx = fmaxf(mx, v);
    }
    mx = fmaxf(mx, __shfl_xor(mx, 32));
    if (__any(mx > mrow + 8.0f)){                   // defer-max (T13)
      float mn = fmaxf(mrow, mx);
      float scl = __expf(mrow - mn);
      mrow = mn; lrow *= scl;
      #pragma unroll
      for (int ht = 0; ht < 8; ++ht) o[ht] *= scl;
    }
    float rs = 0.0f;
    #pragma unroll
    for (int r = 0; r < 16; ++r){ p[r] = __expf(p[r] - mrow); rs += p[r]; }
    rs += __shfl_xor(rs, 32);
    lrow += rs;

    // P -> bf16 A-frags in registers: cvt_pk pairs + permlane32_swap (T12)
    uint32_t w0, w1, w2, w3, w4, w5, w6, w7;
    w0 = cvtpk(p[0], p[1]);   w2 = cvtpk(p[4], p[5]);   plswap(w0, w2);
    w1 = cvtpk(p[2], p[3]);   w3 = cvtpk(p[6], p[7]);   plswap(w1, w3);
    w4 = cvtpk(p[8], p[9]);   w6 = cvtpk(p[12], p[13]); plswap(w4, w6);
    w5 = cvtpk(p[10], p[11]); w7 = cvtpk(p[14], p[15]); plswap(w5, w7);
    u32x4 t0v = {w0, w1, w2, w3};
    u32x4 t1v = {w4, w5, w6, w7};
    bf16x8 pa0 = __builtin_bit_cast(bf16x8, t0v);   // k = s 0..15
    bf16x8 pa1 = __builtin_bit_cast(bf16x8, t1v);   // k = s 16..31

    // PV: O[q][h], B = V[s][h] from subtiled LDS (conflict-free b128)
    __builtin_amdgcn_s_setprio(1);
    #pragma unroll
    for (int ht = 0; ht < 8; ++ht){
      bf16x8 bv0 = ldbf8(&vsb[(size_t)hi*2048       + (ht*32 + lc)*8]);
      o[ht] = mfma32(pa0, bv0, o[ht]);
      bf16x8 bv1 = ldbf8(&vsb[(size_t)(2 + hi)*2048 + (ht*32 + lc)*8]);
      o[ht] = mfma32(pa1, bv1, o[ht]);
    }
    __builtin_amdgcn_s_setprio(0);
    __syncthreads();                 // drains staging: next tile ready, buffers reusable
  }

  // epilogue: unscaled partial o (f32) + per-q m,l
  float* pop = (sh == 3) ? po3 : po + (size_t)sh * 4194304;
  #pragma unroll
  for (int ht = 0; ht < 8; ++ht)
    #pragma unroll
    for (int r = 0; r < 16; ++r){
      int qr = (r & 3) + 8*(r >> 2) + hi*4;
      pop[(size_t)(b*512 + t0w + qr)*1024 + n*256 + ht*32 + lc] = o[ht][r];
    }
  if (hi == 0){
    int mlidx = sh*16384 + (b*512 + t0w + lc)*4 + n;
    pm[mlidx] = mrow;
    pl[mlidx] = lrow;
  }
}

// ---------------- merge split-S partials -> enc bf16 ----------------
__global__ __launch_bounds__(64) void merge_k(const float* __restrict__ po,
                                              const float* __restrict__ po3,
                                              const float* __restrict__ pm,
                                              const float* __restrict__ pl,
                                              uint16_t* __restrict__ enc){
  int idx = blockIdx.x;                  // 16384 = (b*512+t)*4 + n
  int row = idx >> 2, n = idx & 3;
  float m = -1e30f;
  #pragma unroll
  for (int h = 0; h < 4; ++h) m = fmaxf(m, pm[h*16384 + idx]);
  float w[4], lsum = 0.0f;
  #pragma unroll
  for (int h = 0; h < 4; ++h){
    w[h] = __expf(pm[h*16384 + idx] - m);
    lsum += pl[h*16384 + idx] * w[h];
  }
  float inv = 1.0f / lsum;
  size_t off = (size_t)row*1024 + n*256 + threadIdx.x*4;
  f32x4 acc = {};
  #pragma unroll
  for (int h = 0; h < 3; ++h){
    f32x4 a = *(const f32x4*)(po + (size_t)h*4194304 + off);
    acc[0] += a[0]*w[h]; acc[1] += a[1]*w[h]; acc[2] += a[2]*w[h]; acc[3] += a[3]*w[h];
  }
  f32x4 a3 = *(const f32x4*)(po3 + off);
  acc[0] += a3[0]*w[3]; acc[1] += a3[1]*w[3]; acc[2] += a3[2]*w[3]; acc[3] += a3[3]*w[3];
  u16x4 ov;
  #pragma unroll
  for (int r = 0; r < 4; ++r) ov[r] = f2bf(acc[r] * inv);
  *(u16x4*)(enc + off) = ov;
}

// ---------------- launcher ----------------
extern "C" void kernel_launch(void* const* d_in, const int* in_sizes, int n_in,
                              void* d_out, int out_size, void* d_ws, size_t ws_size,
                              hipStream_t stream){
  const float* x    = (const float*)d_in[0];   // [8][512][1024]
  const float* mem  = (const float*)d_in[1];   // [8][2048][1024]
  const void*  mask = d_in[2];                 // [8][2048]
  const float* rms  = (const float*)d_in[3];   // [1024]
  const float* qw   = (const float*)d_in[4];   // [4][1024][256]
  const float* kvw  = (const float*)d_in[5];   // [2][1][1024][256]
  const float* ow   = (const float*)d_in[6];   // [4][256][1024]
  float* out = (float*)d_out;                  // [8][512][1024] f32
  char* ws = (char*)d_ws;

  const size_t MB = 1ull << 20;
  uint16_t* xn   = (uint16_t*)(ws + 0);        // 8MB  bf16 [4096][1024]
  uint16_t* enc  = (uint16_t*)(ws + 0);        // 8MB  reuse (xn dead before merge)
  uint16_t* qb   = (uint16_t*)(ws + 8*MB);     // 8MB  q bf16 [4096][1024]
  uint16_t* kb   = (uint16_t*)(ws + 16*MB);    // 8MB  k bf16 [16384][256]
  uint16_t* vt   = (uint16_t*)(ws + 24*MB);    // 8MB  Vt bf16 [8][256][2048]
  uint16_t* wq   = (uint16_t*)(ws + 32*MB);    // 2MB
  uint16_t* wkv  = (uint16_t*)(ws + 34*MB);    // 1MB
  uint16_t* wout = (uint16_t*)(ws + 35*MB);    // 2MB
  float*    bias = (float*)   (ws + 37*MB);    // 64KB
  float*    pm   = (float*)   (ws + 37*MB + 65536);            // 256KB [4][16384]
  float*    pl   = (float*)   (ws + 37*MB + 65536 + 262144);   // 256KB
  int*      flag = (int*)     (ws + 37*MB + 65536 + 524288);
  uint16_t* mn   = (uint16_t*)(ws + 38*MB);    // 32MB bf16 [16384][1024] (dead after kv GEMM)
  float*    po   = (float*)   (ws + 38*MB);    // 48MB f32 [3][4096][1024] (reuses mn)
  float*    po3  = out;                        // 16MB 4th partial lives in d_out

  hipMemsetAsync(flag, 0, 4, stream);
  detect_mask_k<<<1, 256, 0, stream>>>((const uint32_t*)mask, flag);
  expand_mask_k<<<64, 256, 0, stream>>>(mask, flag, bias);

  rmsnorm_k<<<4096,  256, 0, stream>>>(x,   xn, rms);
  rmsnorm_k<<<16384, 256, 0, stream>>>(mem, mn, rms);

  transpose_cast_k<<<dim3(8,32,4),  dim3(32,8), 0, stream>>>(qw,  wq,   256, 1024, 1024*256, 256*1024);
  transpose_cast_k<<<dim3(8,32,2),  dim3(32,8), 0, stream>>>(kvw, wkv,  256, 1024, 1024*256, 256*1024);
  transpose_cast_k<<<dim3(32,32,1), dim3(32,8), 0, stream>>>(ow,  wout, 1024, 1024, 0, 0);

  gemm_bt_k<1><<<dim3(8, 32),  256, 0, stream>>>(xn, wq,  nullptr, qb, nullptr, nullptr, 4096, 1024, 1024);
  gemm_bt_k<2><<<dim3(4, 128), 256, 0, stream>>>(mn, wkv, nullptr, nullptr, kb, vt, 16384, 512, 1024);

  rope_q_k<<<8192, 256, 0, stream>>>(qb);
  rope_k_k<<<8192, 256, 0, stream>>>(kb);

  attn_k<<<256, 512, 0, stream>>>(qb, kb, vt, bias, po, po3, pm, pl);
  merge_k<<<16384, 64, 0, stream>>>(po, po3, pm, pl, enc);

  gemm_bt_k<0><<<dim3(8, 32), 256, 0, stream>>>(enc, wout, out, nullptr, nullptr, nullptr, 4096, 1024, 1024);
}